// Round 6
// baseline (306.940 us; speedup 1.0000x reference)
//
#include <hip/hip_runtime.h>
#include <stdint.h>
#include <math.h>

// Algebra (validated R3-R7):
//   q = x0 @ Wq + bq                       (bk is softmax-invariant, dropped)
//   r[h][d]   = sum_c q[h*64+c] * Wk[d][h*64+c]       (no transpose needed)
//   logits[h][n] = (r[h] . x[n]) / 8
//   p = softmax_n ; y[h] = sum_n p[h][n] x[n]
//   ctx[h*64+u] = sum_d y[h][d] Wv[d][h*64+u] + bv
//   out = ctx @ Wo + bo
// R13: spills fixed (WRITE 6.6MB->512B) but dur 134us flat: Little's-law
// analysis -> x-stream is MLP-starved (2KB in flight/CU = ~5GB/s/CU).
// R14 (this round): global_load_lds DMA staging, TRIPLE-buffered (3x32KB),
// counted vmcnt(2) waits, raw s_barrier in loop (no vmcnt(0) drain).
// 2 tiles always in flight = 64KB/CU outstanding. LDS overlays keep 119KB.

#define NT 16  // x rows per tile; 16 tiles of 16 = 256

__device__ __forceinline__ void gload_lds16(const float* g, float* l) {
  __builtin_amdgcn_global_load_lds(
      (const __attribute__((address_space(1))) void*)g,
      (__attribute__((address_space(3))) void*)l, 16, 0, 0);
}

__global__ __launch_bounds__(1024, 4) void fused_kernel(
    const float* __restrict__ x,
    const float* __restrict__ Wq, const float* __restrict__ bq,
    const float* __restrict__ Wk,
    const float* __restrict__ Wv, const float* __restrict__ bv,
    const float* __restrict__ Wo, const float* __restrict__ bo,
    float* __restrict__ out) {
  const int bs = blockIdx.x;
  const int t = threadIdx.x;
  const int w = t >> 6, lane = t & 63;
  const float* xb = x + (long)bs * 131072;  // x[bs][n][d], 256*512

  // arena (floats): [0..24575] 3 x-tile bufs of 8192 (32KB each).
  //   pre-loop : P0 red_s overlay at +16384 (buf2; bufs 0/1 are DMA targets)
  //   post-loop: ypar at +0, y_s at +4096, red_s at +16384 (all bufs dead)
  // [24576..28671] r_s (dead after rv load, but no later user needs it)
  __shared__ float arena[28672];                    // 112 KB
  __shared__ float q_s[512], x0_s[512], ctx_s[512]; // 6 KB
  __shared__ float pt_s[8][NT], f_s[8], s_s[8];
  float* const r_s = arena + 24576;

  // ---- prologue: stage cls row; issue tile 0/1 DMA (land during P0/P1) ----
  if (t < 128) *(float4*)&x0_s[t * 4] = *(const float4*)&xb[t * 4];
  {
    // thread t stages tile words 4t and 4096+4t; per-wave uniform LDS base.
    float* b0 = arena;         // buf 0 <- tile 0
    float* b1 = arena + 8192;  // buf 1 <- tile 1
    gload_lds16(&xb[(long)t * 4],           b0 + w * 256);
    gload_lds16(&xb[4096 + (long)t * 4],    b0 + 4096 + w * 256);
    gload_lds16(&xb[8192 + (long)t * 4],    b1 + w * 256);
    gload_lds16(&xb[12288 + (long)t * 4],   b1 + 4096 + w * 256);
  }
  __syncthreads();

  // ---- P0: q = x0 @ Wq + bq (8-way k-split; red_s overlay in buf2) ----
  {
    float (*red_s)[512] = (float (*)[512])(arena + 16384);
    const int j4 = (t & 127) * 4;
    const int kq = t >> 7;  // 0..7, 64 k's each
    float4 a = make_float4(0.f, 0.f, 0.f, 0.f);
    const float* wp = Wq + (long)(kq * 64) * 512 + j4;
    const float* ap = &x0_s[kq * 64];
#pragma unroll 8
    for (int k = 0; k < 64; ++k) {
      float4 wv = *(const float4*)&wp[(long)k * 512];
      float av = ap[k];
      a.x += av * wv.x; a.y += av * wv.y; a.z += av * wv.z; a.w += av * wv.w;
    }
    if (kq > 0) *(float4*)&red_s[kq - 1][j4] = a;
    __syncthreads();
    if (kq == 0) {
#pragma unroll
      for (int rr = 0; rr < 7; ++rr) {
        float4 b = *(const float4*)&red_s[rr][j4];
        a.x += b.x; a.y += b.y; a.z += b.z; a.w += b.w;
      }
      float4 bb = *(const float4*)&bq[j4];
      a.x += bb.x; a.y += bb.y; a.z += bb.z; a.w += bb.w;
      *(float4*)&q_s[j4] = a;
    }
  }
  __syncthreads();

  // ---- P1: r[h][d]; thread t -> row d = t>>1, heads (t&1)*4..+3 ----
  {
    const int d = t >> 1, hh = t & 1;
    const float* wrow = Wk + (long)d * 512 + hh * 256;
#pragma unroll
    for (int hi = 0; hi < 4; ++hi) {
      const int h = hh * 4 + hi;
      const float* qp = &q_s[h * 64];
      float racc = 0.f;
#pragma unroll
      for (int c4 = 0; c4 < 16; ++c4) {
        float4 wv = *(const float4*)&wrow[hi * 64 + c4 * 4];
        racc += qp[c4 * 4 + 0] * wv.x + qp[c4 * 4 + 1] * wv.y +
                qp[c4 * 4 + 2] * wv.z + qp[c4 * 4 + 3] * wv.w;
      }
      r_s[h * 512 + d] = racc;
    }
  }
  __syncthreads();

  // ---- rv: wave w loads its head group (4 heads, 32 regs) ----
  const int hg = w & 1;        // head group: heads hg*4 .. hg*4+3
  const int rw = w >> 1;       // row-within-pass 0..7
  float rv[4][8];
#pragma unroll
  for (int hi = 0; hi < 4; ++hi) {
    const int h = hg * 4 + hi;
    float4 a = *(const float4*)&r_s[h * 512 + lane * 8];
    float4 b = *(const float4*)&r_s[h * 512 + lane * 8 + 4];
    rv[hi][0] = a.x; rv[hi][1] = a.y; rv[hi][2] = a.z; rv[hi][3] = a.w;
    rv[hi][4] = b.x; rv[hi][5] = b.y; rv[hi][6] = b.z; rv[hi][7] = b.w;
  }

  // ---- online-softmax state ----
  float accy[8] = {0.f, 0.f, 0.f, 0.f, 0.f, 0.f, 0.f, 0.f};
  float m_h = -INFINITY, s_h = 0.f;  // wave w<8 tracks head w
  const int dcol = t & 511, halfn = t >> 9;

  // ---- main loop: 16 tiles, triple-buffer, counted vmcnt ----
  // steady state: tiles t+1, t+2 in flight (4 DMA loads). vmcnt(2) at iter
  // top guarantees tile t landed. Raw s_barrier (NOT __syncthreads: that
  // would emit vmcnt(0) and drain the pipeline).
  for (int tile = 0; tile < 16; ++tile) {
    const int cur = tile % 3;
    const float* xt = arena + cur * 8192;

    if (tile < 15) {
      asm volatile("s_waitcnt vmcnt(2)" ::: "memory");
    } else {
      asm volatile("s_waitcnt vmcnt(0)" ::: "memory");
    }
    __builtin_amdgcn_sched_barrier(0);
    __builtin_amdgcn_s_barrier();   // A: tile ready + prev-iter readers done
    __builtin_amdgcn_sched_barrier(0);

    // issue DMA for tile+2 into buf (tile+2)%3 (its readers pre-date A)
    if (tile + 2 < 16) {
      const float* src = xb + (long)(tile + 2) * 8192;
      float* dst = arena + ((tile + 2) % 3) * 8192;
      gload_lds16(&src[(long)t * 4],        dst + w * 256);
      gload_lds16(&src[4096 + (long)t * 4], dst + 4096 + w * 256);
    }

    // logits: 2 waves per row (head groups), 2 rows per wave (ILP)
#pragma unroll
    for (int pass = 0; pass < 2; ++pass) {
      const int row = pass * 8 + rw;
      const float* xr = &xt[row * 512 + lane * 8];
      float4 xa = *(const float4*)xr;
      float4 xb4 = *(const float4*)(xr + 4);
      float acc[4];
#pragma unroll
      for (int hi = 0; hi < 4; ++hi)
        acc[hi] = xa.x * rv[hi][0] + xa.y * rv[hi][1] + xa.z * rv[hi][2] + xa.w * rv[hi][3]
                + xb4.x * rv[hi][4] + xb4.y * rv[hi][5] + xb4.z * rv[hi][6] + xb4.w * rv[hi][7];
#pragma unroll
      for (int j = 0; j < 2; ++j) {
        float v = (lane & 2) ? acc[j] : acc[j + 2];
        float tt = __shfl_xor(v, 2);
        acc[j] = ((lane & 2) ? acc[j + 2] : acc[j]) + tt;
      }
      {
        float v = (lane & 1) ? acc[0] : acc[1];
        float tt = __shfl_xor(v, 1);
        acc[0] = ((lane & 1) ? acc[1] : acc[0]) + tt;
      }
      acc[0] += __shfl_xor(acc[0], 4);
      acc[0] += __shfl_xor(acc[0], 8);
      acc[0] += __shfl_xor(acc[0], 16);
      acc[0] += __shfl_xor(acc[0], 32);
      if (lane < 4) pt_s[hg * 4 + lane][row] = acc[0] * 0.125f;
    }
    asm volatile("s_waitcnt lgkmcnt(0)" ::: "memory");
    __builtin_amdgcn_sched_barrier(0);
    __builtin_amdgcn_s_barrier();   // B: logits in pt_s
    __builtin_amdgcn_sched_barrier(0);

    // online-softmax update: wave w<8 owns head w; lanes 0..15 hold the tile
    if (w < 8) {
      float l = (lane < 16) ? pt_s[w][lane] : -3.0e38f;
      float tm = l;
#pragma unroll
      for (int o = 8; o; o >>= 1) tm = fmaxf(tm, __shfl_xor(tm, o));
      float m_new = fmaxf(m_h, tm);
      float e = __expf(l - m_new);
      float ts = e;
#pragma unroll
      for (int o = 8; o; o >>= 1) ts += __shfl_xor(ts, o);
      float f = __expf(m_h - m_new);  // tile 0: exp(-inf)=0
      s_h = s_h * f + ts;
      m_h = m_new;
      if (lane == 0) f_s[w] = f;
      if (lane < 16) pt_s[w][lane] = e;
    }
    asm volatile("s_waitcnt lgkmcnt(0)" ::: "memory");
    __builtin_amdgcn_sched_barrier(0);
    __builtin_amdgcn_s_barrier();   // C: probabilities + f_s ready
    __builtin_amdgcn_sched_barrier(0);

    // y accumulate: thread owns d=dcol, n-half halfn (8 n's per tile)
    {
#pragma unroll
      for (int h = 0; h < 8; ++h) accy[h] *= f_s[h];
#pragma unroll
      for (int n4 = 0; n4 < 2; ++n4) {
        const int nb = halfn * 8 + n4 * 4;
        float xv0 = xt[(nb + 0) * 512 + dcol];
        float xv1 = xt[(nb + 1) * 512 + dcol];
        float xv2 = xt[(nb + 2) * 512 + dcol];
        float xv3 = xt[(nb + 3) * 512 + dcol];
#pragma unroll
        for (int h = 0; h < 8; ++h) {
          float4 p4 = *(const float4*)&pt_s[h][nb];
          accy[h] += p4.x * xv0 + p4.y * xv1 + p4.z * xv2 + p4.w * xv3;
        }
      }
    }
    // no end barrier: next iter's barrier A orders y-reads vs DMA reuse
  }

  // ---- finalize y: combine n-halves, normalize (overlays: bufs dead) ----
  if (w < 8 && lane == 0) s_s[w] = s_h;
  __syncthreads();   // all xt reads done; safe to overlay
  float* ypar = arena;          // [8][512]
  float* y_sp = arena + 4096;   // [8][520]
  if (halfn == 1) {
#pragma unroll
    for (int h = 0; h < 8; ++h) ypar[h * 512 + dcol] = accy[h];
  }
  __syncthreads();
  if (halfn == 0) {
#pragma unroll
    for (int h = 0; h < 8; ++h)
      y_sp[h * 520 + dcol] = (accy[h] + ypar[h * 512 + dcol]) * (1.f / s_s[h]);
  }
  __syncthreads();

  // ---- P5: ctx[o] = sum_d y[h(o)][d] * Wv[d][o] + bv (8-way k-split) ----
  {
    float (*red_s)[512] = (float (*)[512])(arena + 16384);
    const int o4 = (t & 127) * 4;
    const int kq = t >> 7;
    const int h0 = o4 >> 6;
    float4 a = make_float4(0.f, 0.f, 0.f, 0.f);
    const float* wp = Wv + (long)(kq * 64) * 512 + o4;
    const float* yp2 = &y_sp[h0 * 520 + kq * 64];
#pragma unroll 8
    for (int k = 0; k < 64; ++k) {
      float4 wv = *(const float4*)&wp[(long)k * 512];
      float yv = yp2[k];
      a.x += yv * wv.x; a.y += yv * wv.y; a.z += yv * wv.z; a.w += yv * wv.w;
    }
    if (kq > 0) *(float4*)&red_s[kq - 1][o4] = a;
    __syncthreads();
    if (kq == 0) {
#pragma unroll
      for (int rr = 0; rr < 7; ++rr) {
        float4 b = *(const float4*)&red_s[rr][o4];
        a.x += b.x; a.y += b.y; a.z += b.z; a.w += b.w;
      }
      float4 bb = *(const float4*)&bv[o4];
      a.x += bb.x; a.y += bb.y; a.z += bb.z; a.w += bb.w;
      *(float4*)&ctx_s[o4] = a;
    }
  }
  __syncthreads();

  // ---- P6: out = ctx @ Wo + bo (8-way k-split) ----
  {
    float (*red_s)[512] = (float (*)[512])(arena + 16384);
    const int j4 = (t & 127) * 4;
    const int kq = t >> 7;
    float4 a = make_float4(0.f, 0.f, 0.f, 0.f);
    const float* wp = Wo + (long)(kq * 64) * 512 + j4;
    const float* cp = &ctx_s[kq * 64];
#pragma unroll 8
    for (int k = 0; k < 64; ++k) {
      float4 wv = *(const float4*)&wp[(long)k * 512];
      float cv = cp[k];
      a.x += cv * wv.x; a.y += cv * wv.y; a.z += cv * wv.z; a.w += cv * wv.w;
    }
    if (kq > 0) *(float4*)&red_s[kq - 1][j4] = a;
    __syncthreads();
    if (kq == 0) {
#pragma unroll
      for (int rr = 0; rr < 7; ++rr) {
        float4 b = *(const float4*)&red_s[rr][j4];
        a.x += b.x; a.y += b.y; a.z += b.z; a.w += b.w;
      }
      float4 bb = *(const float4*)&bo[j4];
      a.x += bb.x; a.y += bb.y; a.z += bb.z; a.w += bb.w;
      *(float4*)&out[(long)bs * 512 + j4] = a;
    }
  }
}

extern "C" void kernel_launch(void* const* d_in, const int* in_sizes, int n_in,
                              void* d_out, int out_size, void* d_ws, size_t ws_size,
                              hipStream_t stream) {
  (void)in_sizes; (void)n_in; (void)out_size; (void)d_ws; (void)ws_size;
  const float* x  = (const float*)d_in[0];
  const float* Wq = (const float*)d_in[1];
  const float* bq = (const float*)d_in[2];
  const float* Wk = (const float*)d_in[3];
  // d_in[4] = bk: softmax-invariant, unused
  const float* Wv = (const float*)d_in[5];
  const float* bv = (const float*)d_in[6];
  const float* Wo = (const float*)d_in[7];
  const float* bo = (const float*)d_in[8];
  float* out = (float*)d_out;

  fused_kernel<<<256, 1024, 0, stream>>>(x, Wq, bq, Wk, Wv, bv, Wo, bo, out);
}

// Round 10
// 296.435 us; speedup vs baseline: 1.0354x; 1.0354x over previous
//
#include <hip/hip_runtime.h>
#include <stdint.h>
#include <math.h>

// Algebra (validated R3-R7):
//   q = x0 @ Wq + bq                       (bk is softmax-invariant, dropped)
//   r[h][d]   = sum_c q[h*64+c] * Wk[d][h*64+c]       (no transpose needed)
//   logits[h][n] = (r[h] . x[n]) / 8
//   p = softmax_n ; y[h] = sum_n p[h][n] x[n]
//   ctx[h*64+u] = sum_d y[h][d] Wv[d][h*64+u] + bv
//   out = ctx @ Wo + bo
// R14 post-mortem: inline-asm barriers + sched pins poisoned codegen
// (WRITE_SIZE 69MB of scratch) -> 174us. Reverted all asm.
// R15..R18: NO x LDS staging at all.
//   - logits: rows read global->reg, next tile's rows reg-prefetched (issued
//     after softmax barrier, consumed after loop back-edge: no barrier between
//     issue and use, so no vmcnt(0) drain kills the prefetch)
//   - y: reads x[n][dcol] from global (tile is L2-hot: logits touched it one
//     barrier earlier). Kills barrier A, staging writes, x bank conflicts.
//   - pt_s/f_s double-buffered by tile parity -> 2 barriers/tile (was 3)
// (R18 = R15 resubmitted: 4th infra failure; deadlock/OOB/resource audits clean)

#define NT 16  // x rows per tile; 16 tiles of 16 = 256

__global__ __launch_bounds__(1024, 4) void fused_kernel(
    const float* __restrict__ x,
    const float* __restrict__ Wq, const float* __restrict__ bq,
    const float* __restrict__ Wk,
    const float* __restrict__ Wv, const float* __restrict__ bv,
    const float* __restrict__ Wo, const float* __restrict__ bo,
    float* __restrict__ out) {
  const int bs = blockIdx.x;
  const int t = threadIdx.x;
  const int w = t >> 6, lane = t & 63;
  const float* xb = x + (long)bs * 131072;  // x[bs][n][d], 256*512

  __shared__ float q_s[512], x0_s[512], ctx_s[512];  // 6 KB
  __shared__ float r_s[4096];          // 16 KB
  __shared__ float red_s[7][512];      // 14 KB
  __shared__ float ypar[8][512];       // 16 KB
  __shared__ float y_sp[8][520];       // 16.6 KB
  __shared__ float pt_s[2][8][NT];     // 1 KB, double-buffered by tile parity
  __shared__ float f_s[2][8];
  __shared__ float s_s[8];

  const int hg = w & 1;        // head group: heads hg*4 .. hg*4+3
  const int rw = w >> 1;       // row-within-pass 0..7

  // ---- prologue: stage cls row; preload tile-0 logits rows into regs ----
  if (t < 128) *(float4*)&x0_s[t * 4] = *(const float4*)&xb[t * 4];
  float4 c00 = *(const float4*)&xb[(long)rw * 512 + lane * 8];
  float4 c01 = *(const float4*)&xb[(long)rw * 512 + lane * 8 + 4];
  float4 c10 = *(const float4*)&xb[(long)(8 + rw) * 512 + lane * 8];
  float4 c11 = *(const float4*)&xb[(long)(8 + rw) * 512 + lane * 8 + 4];
  __syncthreads();

  // ---- P0: q = x0 @ Wq + bq (8-way k-split over 1024 threads) ----
  {
    const int j4 = (t & 127) * 4;
    const int kq = t >> 7;  // 0..7, 64 k's each
    float4 a = make_float4(0.f, 0.f, 0.f, 0.f);
    const float* wp = Wq + (long)(kq * 64) * 512 + j4;
    const float* ap = &x0_s[kq * 64];
#pragma unroll 8
    for (int k = 0; k < 64; ++k) {
      float4 wv = *(const float4*)&wp[(long)k * 512];
      float av = ap[k];
      a.x += av * wv.x; a.y += av * wv.y; a.z += av * wv.z; a.w += av * wv.w;
    }
    if (kq > 0) *(float4*)&red_s[kq - 1][j4] = a;
    __syncthreads();
    if (kq == 0) {
#pragma unroll
      for (int rr = 0; rr < 7; ++rr) {
        float4 b = *(const float4*)&red_s[rr][j4];
        a.x += b.x; a.y += b.y; a.z += b.z; a.w += b.w;
      }
      float4 bb = *(const float4*)&bq[j4];
      a.x += bb.x; a.y += bb.y; a.z += bb.z; a.w += bb.w;
      *(float4*)&q_s[j4] = a;
    }
  }
  __syncthreads();

  // ---- P1: r[h][d]; thread t -> row d = t>>1, heads (t&1)*4..+3 ----
  {
    const int d = t >> 1, hh = t & 1;
    const float* wrow = Wk + (long)d * 512 + hh * 256;
#pragma unroll
    for (int hi = 0; hi < 4; ++hi) {
      const int h = hh * 4 + hi;
      const float* qp = &q_s[h * 64];
      float racc = 0.f;
#pragma unroll
      for (int c4 = 0; c4 < 16; ++c4) {
        float4 wv = *(const float4*)&wrow[hi * 64 + c4 * 4];
        racc += qp[c4 * 4 + 0] * wv.x + qp[c4 * 4 + 1] * wv.y +
                qp[c4 * 4 + 2] * wv.z + qp[c4 * 4 + 3] * wv.w;
      }
      r_s[h * 512 + d] = racc;
    }
  }
  __syncthreads();

  // ---- rv: wave w loads its head group (4 heads, 32 regs) ----
  float rv[4][8];
#pragma unroll
  for (int hi = 0; hi < 4; ++hi) {
    const int h = hg * 4 + hi;
    float4 a = *(const float4*)&r_s[h * 512 + lane * 8];
    float4 b = *(const float4*)&r_s[h * 512 + lane * 8 + 4];
    rv[hi][0] = a.x; rv[hi][1] = a.y; rv[hi][2] = a.z; rv[hi][3] = a.w;
    rv[hi][4] = b.x; rv[hi][5] = b.y; rv[hi][6] = b.z; rv[hi][7] = b.w;
  }

  // ---- online-softmax state ----
  float accy[8] = {0.f, 0.f, 0.f, 0.f, 0.f, 0.f, 0.f, 0.f};
  float m_h = -INFINITY, s_h = 0.f;  // wave w<8 tracks head w
  const int dcol = t & 511, halfn = t >> 9;

  for (int tile = 0; tile < 16; ++tile) {
    const int b = tile & 1;

    // logits: 2 rows per wave from regs, 4 heads (head group hg)
    {
      float acc[4];
      // pass 0: row rw
#pragma unroll
      for (int hi = 0; hi < 4; ++hi)
        acc[hi] = c00.x * rv[hi][0] + c00.y * rv[hi][1] + c00.z * rv[hi][2] + c00.w * rv[hi][3]
                + c01.x * rv[hi][4] + c01.y * rv[hi][5] + c01.z * rv[hi][6] + c01.w * rv[hi][7];
#pragma unroll
      for (int j = 0; j < 2; ++j) {
        float v = (lane & 2) ? acc[j] : acc[j + 2];
        float tt = __shfl_xor(v, 2);
        acc[j] = ((lane & 2) ? acc[j + 2] : acc[j]) + tt;
      }
      {
        float v = (lane & 1) ? acc[0] : acc[1];
        float tt = __shfl_xor(v, 1);
        acc[0] = ((lane & 1) ? acc[1] : acc[0]) + tt;
      }
      acc[0] += __shfl_xor(acc[0], 4);
      acc[0] += __shfl_xor(acc[0], 8);
      acc[0] += __shfl_xor(acc[0], 16);
      acc[0] += __shfl_xor(acc[0], 32);
      if (lane < 4) pt_s[b][hg * 4 + lane][rw] = acc[0] * 0.125f;
      // pass 1: row 8+rw
#pragma unroll
      for (int hi = 0; hi < 4; ++hi)
        acc[hi] = c10.x * rv[hi][0] + c10.y * rv[hi][1] + c10.z * rv[hi][2] + c10.w * rv[hi][3]
                + c11.x * rv[hi][4] + c11.y * rv[hi][5] + c11.z * rv[hi][6] + c11.w * rv[hi][7];
#pragma unroll
      for (int j = 0; j < 2; ++j) {
        float v = (lane & 2) ? acc[j] : acc[j + 2];
        float tt = __shfl_xor(v, 2);
        acc[j] = ((lane & 2) ? acc[j + 2] : acc[j]) + tt;
      }
      {
        float v = (lane & 1) ? acc[0] : acc[1];
        float tt = __shfl_xor(v, 1);
        acc[0] = ((lane & 1) ? acc[1] : acc[0]) + tt;
      }
      acc[0] += __shfl_xor(acc[0], 4);
      acc[0] += __shfl_xor(acc[0], 8);
      acc[0] += __shfl_xor(acc[0], 16);
      acc[0] += __shfl_xor(acc[0], 32);
      if (lane < 4) pt_s[b][hg * 4 + lane][8 + rw] = acc[0] * 0.125f;
    }
    __syncthreads();   // B1: pt_s[b] logits visible

    // online-softmax update: wave w<8 owns head w; lanes 0..15 hold the tile
    if (w < 8) {
      float l = (lane < 16) ? pt_s[b][w][lane] : -3.0e38f;
      float tm = l;
#pragma unroll
      for (int o = 8; o; o >>= 1) tm = fmaxf(tm, __shfl_xor(tm, o));
      float m_new = fmaxf(m_h, tm);
      float e = __expf(l - m_new);
      float ts = e;
#pragma unroll
      for (int o = 8; o; o >>= 1) ts += __shfl_xor(ts, o);
      float f = __expf(m_h - m_new);  // tile 0: exp(-inf)=0
      s_h = s_h * f + ts;
      m_h = m_new;
      if (lane == 0) f_s[b][w] = f;
      if (lane < 16) pt_s[b][w][lane] = e;
    }
    __syncthreads();   // B2: e + f ready

    // prefetch next tile's logits rows (consumed at next loop-top logits;
    // no barrier between issue and use -> latency hides under y phase)
    float4 n00, n01, n10, n11;
    if (tile < 15) {
      const float* nx = xb + (long)(tile + 1) * 8192;
      n00 = *(const float4*)&nx[(long)rw * 512 + lane * 8];
      n01 = *(const float4*)&nx[(long)rw * 512 + lane * 8 + 4];
      n10 = *(const float4*)&nx[(long)(8 + rw) * 512 + lane * 8];
      n11 = *(const float4*)&nx[(long)(8 + rw) * 512 + lane * 8 + 4];
    }

    // y accumulate from GLOBAL (tile is L2-hot; coalesced per wave)
    {
#pragma unroll
      for (int h = 0; h < 8; ++h) accy[h] *= f_s[b][h];
      const float* xg = xb + ((long)tile * 16 + halfn * 8) * 512 + dcol;
#pragma unroll
      for (int n4 = 0; n4 < 2; ++n4) {
        const int nb = halfn * 8 + n4 * 4;
        float xv0 = xg[(long)(n4 * 4 + 0) * 512];
        float xv1 = xg[(long)(n4 * 4 + 1) * 512];
        float xv2 = xg[(long)(n4 * 4 + 2) * 512];
        float xv3 = xg[(long)(n4 * 4 + 3) * 512];
#pragma unroll
        for (int h = 0; h < 8; ++h) {
          float4 p4 = *(const float4*)&pt_s[b][h][nb];
          accy[h] += p4.x * xv0 + p4.y * xv1 + p4.z * xv2 + p4.w * xv3;
        }
      }
    }
    if (tile < 15) { c00 = n00; c01 = n01; c10 = n10; c11 = n11; }
    // no end barrier: next logits writes pt_s[b^1] (disjoint), softmax(t+1)
    // is after B1(t+1) which orders it against this y phase.
  }

  // ---- finalize y: combine n-halves, normalize ----
  if (w < 8 && lane == 0) s_s[w] = s_h;
  __syncthreads();
  if (halfn == 1) {
#pragma unroll
    for (int h = 0; h < 8; ++h) ypar[h][dcol] = accy[h];
  }
  __syncthreads();
  if (halfn == 0) {
#pragma unroll
    for (int h = 0; h < 8; ++h)
      y_sp[h][dcol] = (accy[h] + ypar[h][dcol]) * (1.f / s_s[h]);
  }
  __syncthreads();

  // ---- P5: ctx[o] = sum_d y[h(o)][d] * Wv[d][o] + bv (8-way k-split) ----
  {
    const int o4 = (t & 127) * 4;
    const int kq = t >> 7;
    const int h0 = o4 >> 6;
    float4 a = make_float4(0.f, 0.f, 0.f, 0.f);
    const float* wp = Wv + (long)(kq * 64) * 512 + o4;
    const float* yp2 = &y_sp[h0][kq * 64];
#pragma unroll 8
    for (int k = 0; k < 64; ++k) {
      float4 wv = *(const float4*)&wp[(long)k * 512];
      float yv = yp2[k];
      a.x += yv * wv.x; a.y += yv * wv.y; a.z += yv * wv.z; a.w += yv * wv.w;
    }
    if (kq > 0) *(float4*)&red_s[kq - 1][o4] = a;
    __syncthreads();
    if (kq == 0) {
#pragma unroll
      for (int rr = 0; rr < 7; ++rr) {
        float4 b = *(const float4*)&red_s[rr][o4];
        a.x += b.x; a.y += b.y; a.z += b.z; a.w += b.w;
      }
      float4 bb = *(const float4*)&bv[o4];
      a.x += bb.x; a.y += bb.y; a.z += bb.z; a.w += bb.w;
      *(float4*)&ctx_s[o4] = a;
    }
  }
  __syncthreads();

  // ---- P6: out = ctx @ Wo + bo (8-way k-split) ----
  {
    const int j4 = (t & 127) * 4;
    const int kq = t >> 7;
    float4 a = make_float4(0.f, 0.f, 0.f, 0.f);
    const float* wp = Wo + (long)(kq * 64) * 512 + j4;
    const float* cp = &ctx_s[kq * 64];
#pragma unroll 8
    for (int k = 0; k < 64; ++k) {
      float4 wv = *(const float4*)&wp[(long)k * 512];
      float cv = cp[k];
      a.x += cv * wv.x; a.y += cv * wv.y; a.z += cv * wv.z; a.w += cv * wv.w;
    }
    if (kq > 0) *(float4*)&red_s[kq - 1][j4] = a;
    __syncthreads();
    if (kq == 0) {
#pragma unroll
      for (int rr = 0; rr < 7; ++rr) {
        float4 b = *(const float4*)&red_s[rr][j4];
        a.x += b.x; a.y += b.y; a.z += b.z; a.w += b.w;
      }
      float4 bb = *(const float4*)&bo[j4];
      a.x += bb.x; a.y += bb.y; a.z += bb.z; a.w += bb.w;
      *(float4*)&out[(long)bs * 512 + j4] = a;
    }
  }
}

extern "C" void kernel_launch(void* const* d_in, const int* in_sizes, int n_in,
                              void* d_out, int out_size, void* d_ws, size_t ws_size,
                              hipStream_t stream) {
  (void)in_sizes; (void)n_in; (void)out_size; (void)d_ws; (void)ws_size;
  const float* x  = (const float*)d_in[0];
  const float* Wq = (const float*)d_in[1];
  const float* bq = (const float*)d_in[2];
  const float* Wk = (const float*)d_in[3];
  // d_in[4] = bk: softmax-invariant, unused
  const float* Wv = (const float*)d_in[5];
  const float* bv = (const float*)d_in[6];
  const float* Wo = (const float*)d_in[7];
  const float* bo = (const float*)d_in[8];
  float* out = (float*)d_out;

  fused_kernel<<<256, 1024, 0, stream>>>(x, Wq, bq, Wk, Wv, bv, Wo, bo, out);
}